// Round 8
// baseline (589.071 us; speedup 1.0000x reference)
//
#include <hip/hip_runtime.h>
#include <math.h>

#define N_NODES 50000
#define N_EDGES 800000

typedef short bf16x8 __attribute__((ext_vector_type(8)));
typedef float f32x4 __attribute__((ext_vector_type(4)));

// ---- exact bf16 split helpers (bit-level RN-even) ----
__device__ __forceinline__ ushort f2bf(float f) {
    unsigned u = __float_as_uint(f);
    u += 0x7fffu + ((u >> 16) & 1u);
    return (ushort)(u >> 16);
}
__device__ __forceinline__ float bf2f(ushort h) {
    return __uint_as_float(((unsigned)h) << 16);
}
__device__ __forceinline__ void split2(float a, ushort& h, ushort& l) {
    h = f2bf(a);
    l = f2bf(a - bf2f(h));
}

// ---------------------------------------------------------------------------
// Weight convert+transpose: W[K][N] f32 -> WThi/WTlo[NP][KP] bf16 (zero-pad)
// ---------------------------------------------------------------------------
__global__ __launch_bounds__(256) void convert_wt_kernel(
    const float* __restrict__ W, int K, int N, int KP, int NP,
    ushort* __restrict__ Th, ushort* __restrict__ Tl)
{
    int i = blockIdx.x * 256 + threadIdx.x;
    if (i >= NP * KP) return;
    int n = i / KP, k = i % KP;
    float v = (k < K && n < N) ? W[(size_t)k * N + n] : 0.f;
    ushort h, l;
    split2(v, h, l);
    Th[(size_t)n * KP + k] = h;
    Tl[(size_t)n * KP + k] = l;
}

// ---------------------------------------------------------------------------
// MFMA-GEMM pieces. Block = 256 thr = 4 waves; tile BM=64 x BN=64 (782 blocks
// -> ~3 blocks/CU); wave tile 32x32 (2x2 mfma 16x16x32 frags); 3 products
// (hh,hl,lh). LDS rows 40 k-slots (80 B) -> frag b128 reads 2-way max (free).
// T14 pipeline: next chunk loaded to regs while MFMA runs on current.
// ---------------------------------------------------------------------------
__device__ __forceinline__ void loadA_planes(
    const ushort* __restrict__ Ahi, const ushort* __restrict__ Alo,
    int lda, int brow, int M, int k0, int tid, uint4* pA)
{
#pragma unroll
    for (int j = 0; j < 2; ++j) {
        int i = j * 256 + tid;
        int pl = i >> 8, s = i & 255, row = s >> 2, q = s & 3;
        int gr = brow + row;
        const ushort* src = pl ? Alo : Ahi;
        uint4 v = make_uint4(0u, 0u, 0u, 0u);
        if (gr < M) v = *(const uint4*)&src[(size_t)gr * lda + k0 + q * 8];
        pA[j] = v;
    }
}

__device__ __forceinline__ void loadB_planes(
    const ushort* __restrict__ WTh, const ushort* __restrict__ WTl,
    int n0, int KP, int k0, int tid, uint4* pB)
{
#pragma unroll
    for (int j = 0; j < 2; ++j) {
        int i = j * 256 + tid;
        int pl = i >> 8, s = i & 255, row = s >> 2, q = s & 3;
        const ushort* src = pl ? WTl : WTh;
        pB[j] = *(const uint4*)&src[(size_t)(n0 + row) * KP + k0 + q * 8];
    }
}

__device__ __forceinline__ void writeAB(
    ushort* sAh, ushort* sAl, ushort* sBh, ushort* sBl,
    int tid, const uint4* pA, const uint4* pB)
{
#pragma unroll
    for (int j = 0; j < 2; ++j) {
        int i = j * 256 + tid;
        int pl = i >> 8, s = i & 255, row = s >> 2, q = s & 3;
        *(uint4*)&(pl ? sAl : sAh)[row * 40 + q * 8] = pA[j];
        *(uint4*)&(pl ? sBl : sBh)[row * 40 + q * 8] = pB[j];
    }
}

__device__ __forceinline__ void mfma_2x2(
    const ushort* sAh, const ushort* sAl,
    const ushort* sBh, const ushort* sBl,
    int lane, int wr, int wc, f32x4 acc[2][2])
{
    bf16x8 ah[2], al[2], bh[2], bl[2];
#pragma unroll
    for (int mi = 0; mi < 2; ++mi) {
        int off = (wr + mi * 16 + (lane & 15)) * 40 + (lane >> 4) * 8;
        ah[mi] = *(const bf16x8*)&sAh[off];
        al[mi] = *(const bf16x8*)&sAl[off];
    }
#pragma unroll
    for (int ni = 0; ni < 2; ++ni) {
        int off = (wc + ni * 16 + (lane & 15)) * 40 + (lane >> 4) * 8;
        bh[ni] = *(const bf16x8*)&sBh[off];
        bl[ni] = *(const bf16x8*)&sBl[off];
    }
#pragma unroll
    for (int mi = 0; mi < 2; ++mi)
#pragma unroll
        for (int ni = 0; ni < 2; ++ni) {
            acc[mi][ni] = __builtin_amdgcn_mfma_f32_16x16x32_bf16(ah[mi], bh[ni], acc[mi][ni], 0, 0, 0);
            acc[mi][ni] = __builtin_amdgcn_mfma_f32_16x16x32_bf16(ah[mi], bl[ni], acc[mi][ni], 0, 0, 0);
            acc[mi][ni] = __builtin_amdgcn_mfma_f32_16x16x32_bf16(al[mi], bh[ni], acc[mi][ni], 0, 0, 0);
        }
}

// ---------------------------------------------------------------------------
// GEMM on pre-split planes: O = A @ W + bias, output split-stored.
// ---------------------------------------------------------------------------
template<int K, int ACT>
__global__ __launch_bounds__(256) void gemm_mfma_kernel(
    const ushort* __restrict__ Ahi, const ushort* __restrict__ Alo, int lda,
    const ushort* __restrict__ WTh, const ushort* __restrict__ WTl,
    const float* __restrict__ bias,
    ushort* __restrict__ Ohi, ushort* __restrict__ Olo, int ldo, int M)
{
    constexpr int NCH = K / 32;
    __shared__ ushort sAh[64 * 40], sAl[64 * 40], sBh[64 * 40], sBl[64 * 40];
    const int tid  = threadIdx.x;
    const int brow = blockIdx.x * 64;
    const int n0   = blockIdx.y * 64;
    const int lane = tid & 63, w = tid >> 6;
    const int wr = (w >> 1) * 32, wc = (w & 1) * 32;

    f32x4 acc[2][2];
#pragma unroll
    for (int mi = 0; mi < 2; ++mi)
#pragma unroll
        for (int ni = 0; ni < 2; ++ni) acc[mi][ni] = (f32x4)0.f;

    uint4 pA[2], pB[2];
    loadA_planes(Ahi, Alo, lda, brow, M, 0, tid, pA);
    loadB_planes(WTh, WTl, n0, K, 0, tid, pB);

    for (int ch = 0; ch < NCH; ++ch) {
        writeAB(sAh, sAl, sBh, sBl, tid, pA, pB);
        __syncthreads();
        if (ch + 1 < NCH) {
            loadA_planes(Ahi, Alo, lda, brow, M, (ch + 1) * 32, tid, pA);
            loadB_planes(WTh, WTl, n0, K, (ch + 1) * 32, tid, pB);
        }
        mfma_2x2(sAh, sAl, sBh, sBl, lane, wr, wc, acc);
        __syncthreads();
    }

#pragma unroll
    for (int mi = 0; mi < 2; ++mi)
#pragma unroll
        for (int ni = 0; ni < 2; ++ni) {
            int col = n0 + wc + ni * 16 + (lane & 15);
            float b = bias[col];
#pragma unroll
            for (int r = 0; r < 4; ++r) {
                int row = brow + wr + mi * 16 + (lane >> 4) * 4 + r;
                if (row < M) {
                    float v = acc[mi][ni][r] + b;
                    if (ACT == 1) v = fmaxf(v, 0.f);
                    ushort h, l;
                    split2(v, h, l);
                    Ohi[(size_t)row * ldo + col] = h;
                    Olo[(size_t)row * ldo + col] = l;
                }
            }
        }
}

// ---------------------------------------------------------------------------
// First layer: A = features f32 [M][500] (split inline), W1T planes [64][512].
// ---------------------------------------------------------------------------
__global__ __launch_bounds__(256) void gemm_feat_kernel(
    const float* __restrict__ A,
    const ushort* __restrict__ WTh, const ushort* __restrict__ WTl,
    const float* __restrict__ bias,
    ushort* __restrict__ Ohi, ushort* __restrict__ Olo, int M)
{
    __shared__ ushort sAh[64 * 40], sAl[64 * 40], sBh[64 * 40], sBl[64 * 40];
    const int tid  = threadIdx.x;
    const int brow = blockIdx.x * 64;
    const int lane = tid & 63, w = tid >> 6;
    const int wr = (w >> 1) * 32, wc = (w & 1) * 32;

    f32x4 acc[2][2];
#pragma unroll
    for (int mi = 0; mi < 2; ++mi)
#pragma unroll
        for (int ni = 0; ni < 2; ++ni) acc[mi][ni] = (f32x4)0.f;

    // feat A chunk: 64 rows x 8 float4-quads = 512 / 256 thr = 2 per thread
    const int frow = tid >> 2, fq = (tid & 3);        // rows tid>>2, quads
    float4 pA[2];
    uint4  pB[2];

    auto loadA_feat = [&](int k0) {
#pragma unroll
        for (int j = 0; j < 2; ++j) {
            int row = frow, q = fq + j * 4;            // q in 0..7
            int gr = brow + row, gk = k0 + q * 4;
            float4 v = make_float4(0.f, 0.f, 0.f, 0.f);
            if (gr < M) {
                const float* ap = A + (size_t)gr * 500;
                if (gk + 3 < 500) {
                    v = *(const float4*)&ap[gk];
                } else {
                    if (gk + 0 < 500) v.x = ap[gk + 0];
                    if (gk + 1 < 500) v.y = ap[gk + 1];
                    if (gk + 2 < 500) v.z = ap[gk + 2];
                    if (gk + 3 < 500) v.w = ap[gk + 3];
                }
            }
            pA[j] = v;
        }
    };
    auto writeA_feat = [&]() {
#pragma unroll
        for (int j = 0; j < 2; ++j) {
            int row = frow, q = fq + j * 4;
            ushort h0, h1, h2, h3, l0, l1, l2, l3;
            split2(pA[j].x, h0, l0); split2(pA[j].y, h1, l1);
            split2(pA[j].z, h2, l2); split2(pA[j].w, h3, l3);
            uint2 hv, lv;
            hv.x = (unsigned)h0 | ((unsigned)h1 << 16);
            hv.y = (unsigned)h2 | ((unsigned)h3 << 16);
            lv.x = (unsigned)l0 | ((unsigned)l1 << 16);
            lv.y = (unsigned)l2 | ((unsigned)l3 << 16);
            *(uint2*)&sAh[row * 40 + q * 4] = hv;
            *(uint2*)&sAl[row * 40 + q * 4] = lv;
        }
    };

    loadA_feat(0);
    loadB_planes(WTh, WTl, 0, 512, 0, tid, pB);

    for (int ch = 0; ch < 16; ++ch) {
        writeA_feat();
#pragma unroll
        for (int j = 0; j < 2; ++j) {
            int i = j * 256 + tid;
            int pl = i >> 8, s = i & 255, row = s >> 2, q = s & 3;
            *(uint4*)&(pl ? sBl : sBh)[row * 40 + q * 8] = pB[j];
        }
        __syncthreads();
        if (ch + 1 < 16) {
            loadA_feat((ch + 1) * 32);
            loadB_planes(WTh, WTl, 0, 512, (ch + 1) * 32, tid, pB);
        }
        mfma_2x2(sAh, sAl, sBh, sBl, lane, wr, wc, acc);
        __syncthreads();
    }

#pragma unroll
    for (int mi = 0; mi < 2; ++mi)
#pragma unroll
        for (int ni = 0; ni < 2; ++ni) {
            int col = wc + ni * 16 + (lane & 15);
            float b = bias[col];
#pragma unroll
            for (int r = 0; r < 4; ++r) {
                int row = brow + wr + mi * 16 + (lane >> 4) * 4 + r;
                if (row < M) {
                    float v = fmaxf(acc[mi][ni][r] + b, 0.f);
                    ushort h, l;
                    split2(v, h, l);
                    Ohi[(size_t)row * 64 + col] = h;
                    Olo[(size_t)row * 64 + col] = l;
                }
            }
        }
}

// ---------------------------------------------------------------------------
// Final: out = sigmoid([X|X1|X2] @ W2 + b2) fp32, K=448, cols 0..49.
// ---------------------------------------------------------------------------
__global__ __launch_bounds__(256) void final_mfma_kernel(
    const ushort* __restrict__ Xhi,  const ushort* __restrict__ Xlo,
    const ushort* __restrict__ X1hi, const ushort* __restrict__ X1lo,
    const ushort* __restrict__ X2hi, const ushort* __restrict__ X2lo,
    const ushort* __restrict__ WTh,  const ushort* __restrict__ WTl,
    const float* __restrict__ b2,
    float* __restrict__ out, int M)
{
    __shared__ ushort sAh[64 * 40], sAl[64 * 40], sBh[64 * 40], sBl[64 * 40];
    const int tid  = threadIdx.x;
    const int brow = blockIdx.x * 64;
    const int lane = tid & 63, w = tid >> 6;
    const int wr = (w >> 1) * 32, wc = (w & 1) * 32;

    f32x4 acc[2][2];
#pragma unroll
    for (int mi = 0; mi < 2; ++mi)
#pragma unroll
        for (int ni = 0; ni < 2; ++ni) acc[mi][ni] = (f32x4)0.f;

    auto getsrc = [&](int ch, const ushort*& Ah, const ushort*& Al, int& lda) {
        if (ch < 2)      { Ah = Xhi  + ch * 32;       Al = Xlo  + ch * 32;       lda = 64;  }
        else if (ch < 6) { Ah = X1hi + (ch - 2) * 32; Al = X1lo + (ch - 2) * 32; lda = 128; }
        else             { Ah = X2hi + (ch - 6) * 32; Al = X2lo + (ch - 6) * 32; lda = 256; }
    };

    uint4 pA[2], pB[2];
    {
        const ushort *Ah, *Al; int lda;
        getsrc(0, Ah, Al, lda);
        loadA_planes(Ah, Al, lda, brow, M, 0, tid, pA);
    }
    loadB_planes(WTh, WTl, 0, 448, 0, tid, pB);

    for (int ch = 0; ch < 14; ++ch) {
        writeAB(sAh, sAl, sBh, sBl, tid, pA, pB);
        __syncthreads();
        if (ch + 1 < 14) {
            const ushort *Ah, *Al; int lda;
            getsrc(ch + 1, Ah, Al, lda);
            loadA_planes(Ah, Al, lda, brow, M, 0, tid, pA);
            loadB_planes(WTh, WTl, 0, 448, (ch + 1) * 32, tid, pB);
        }
        mfma_2x2(sAh, sAl, sBh, sBl, lane, wr, wc, acc);
        __syncthreads();
    }

#pragma unroll
    for (int mi = 0; mi < 2; ++mi)
#pragma unroll
        for (int ni = 0; ni < 2; ++ni) {
            int col = wc + ni * 16 + (lane & 15);
            if (col < 50) {
                float b = b2[col];
#pragma unroll
                for (int r = 0; r < 4; ++r) {
                    int row = brow + wr + mi * 16 + (lane >> 4) * 4 + r;
                    if (row < M) {
                        float v = acc[mi][ni][r] + b;
                        out[(size_t)row * 50 + col] = 1.f / (1.f + expf(-v));
                    }
                }
            }
        }
}

// ---------------------------------------------------------------------------
// CSR build
// ---------------------------------------------------------------------------
__global__ __launch_bounds__(256) void zero_kernel(int* __restrict__ p, int n)
{
    int i = blockIdx.x * 256 + threadIdx.x;
    if (i < n) p[i] = 0;
}

__global__ __launch_bounds__(256) void count_kernel(
    const int* __restrict__ dst, int* __restrict__ counts, int ne)
{
    int e = blockIdx.x * 256 + threadIdx.x;
    if (e < ne) atomicAdd(&counts[dst[e]], 1);
}

__global__ __launch_bounds__(256) void scan1_kernel(
    const int* __restrict__ counts, int* __restrict__ local,
    int* __restrict__ bsum, int n)
{
    __shared__ int sd[256];
    const int t = threadIdx.x;
    const int i = blockIdx.x * 256 + t;
    int c = (i < n) ? counts[i] : 0;
    sd[t] = c;
    __syncthreads();
#pragma unroll
    for (int off = 1; off < 256; off <<= 1) {
        int v = (t >= off) ? sd[t - off] : 0;
        __syncthreads();
        sd[t] += v;
        __syncthreads();
    }
    if (i < n) local[i] = sd[t] - c;
    if (t == 255) bsum[blockIdx.x] = sd[255];
}

__global__ __launch_bounds__(256) void scan2_kernel(
    const int* __restrict__ bsum, int* __restrict__ boff, int nb)
{
    __shared__ int sd[256];
    const int t = threadIdx.x;
    int v = (t < nb) ? bsum[t] : 0;
    sd[t] = v;
    __syncthreads();
#pragma unroll
    for (int off = 1; off < 256; off <<= 1) {
        int u = (t >= off) ? sd[t - off] : 0;
        __syncthreads();
        sd[t] += u;
        __syncthreads();
    }
    if (t < nb) boff[t] = sd[t] - v;
}

__global__ __launch_bounds__(256) void scan3_kernel(
    int* __restrict__ row_ptr, const int* __restrict__ boff,
    int* __restrict__ cursor, int n, int total)
{
    const int i = blockIdx.x * 256 + threadIdx.x;
    if (i < n) {
        int v = row_ptr[i] + boff[blockIdx.x];
        row_ptr[i] = v;
        cursor[i]  = v;
    }
    if (i == 0) row_ptr[n] = total;
}

__global__ __launch_bounds__(256) void fill_kernel(
    const int* __restrict__ src, const int* __restrict__ dst,
    int* __restrict__ cursor, int* __restrict__ elist, int ne)
{
    int e = blockIdx.x * 256 + threadIdx.x;
    if (e < ne) {
        int p = atomicAdd(&cursor[dst[e]], 1);
        elist[p] = src[e];
    }
}

// ---------------------------------------------------------------------------
// Gather aggregation over split planes, edge loop unrolled x2 for MLP.
// ---------------------------------------------------------------------------
template<int D>
__global__ __launch_bounds__(256) void agg_planes_kernel(
    const ushort* __restrict__ hhi, const ushort* __restrict__ hlo, int ldh,
    const int* __restrict__ row_ptr, const int* __restrict__ elist,
    ushort* __restrict__ ohi, ushort* __restrict__ olo, int ldo, int n)
{
    constexpr int LPR = D / 4;                 // lanes per row (16 or 32)
    constexpr int EPI = 64 / LPR;              // edges in flight (4 or 2)
    const int lane = threadIdx.x & 63;
    const int node = blockIdx.x * 4 + (threadIdx.x >> 6);
    if (node >= n) return;
    const int g  = lane / LPR;
    const int c4 = (lane % LPR) * 4;
    const int beg = row_ptr[node], end = row_ptr[node + 1];

    float a0 = 0.f, a1 = 0.f, a2 = 0.f, a3 = 0.f;
    int e = beg + g;
    for (; e + EPI < end; e += 2 * EPI) {
        int s0 = elist[e], s1 = elist[e + EPI];
        uint2 h0 = *(const uint2*)&hhi[(size_t)s0 * ldh + c4];
        uint2 l0 = *(const uint2*)&hlo[(size_t)s0 * ldh + c4];
        uint2 h1 = *(const uint2*)&hhi[(size_t)s1 * ldh + c4];
        uint2 l1 = *(const uint2*)&hlo[(size_t)s1 * ldh + c4];
        a0 += bf2f((ushort)h0.x) + bf2f((ushort)l0.x)
            + bf2f((ushort)h1.x) + bf2f((ushort)l1.x);
        a1 += bf2f((ushort)(h0.x >> 16)) + bf2f((ushort)(l0.x >> 16))
            + bf2f((ushort)(h1.x >> 16)) + bf2f((ushort)(l1.x >> 16));
        a2 += bf2f((ushort)h0.y) + bf2f((ushort)l0.y)
            + bf2f((ushort)h1.y) + bf2f((ushort)l1.y);
        a3 += bf2f((ushort)(h0.y >> 16)) + bf2f((ushort)(l0.y >> 16))
            + bf2f((ushort)(h1.y >> 16)) + bf2f((ushort)(l1.y >> 16));
    }
    if (e < end) {
        int s0 = elist[e];
        uint2 h0 = *(const uint2*)&hhi[(size_t)s0 * ldh + c4];
        uint2 l0 = *(const uint2*)&hlo[(size_t)s0 * ldh + c4];
        a0 += bf2f((ushort)h0.x) + bf2f((ushort)l0.x);
        a1 += bf2f((ushort)(h0.x >> 16)) + bf2f((ushort)(l0.x >> 16));
        a2 += bf2f((ushort)h0.y) + bf2f((ushort)l0.y);
        a3 += bf2f((ushort)(h0.y >> 16)) + bf2f((ushort)(l0.y >> 16));
    }
    if (EPI == 4) {
        a0 += __shfl_xor(a0, 16); a1 += __shfl_xor(a1, 16);
        a2 += __shfl_xor(a2, 16); a3 += __shfl_xor(a3, 16);
    }
    a0 += __shfl_xor(a0, 32); a1 += __shfl_xor(a1, 32);
    a2 += __shfl_xor(a2, 32); a3 += __shfl_xor(a3, 32);

    if (g == 0) {
        ushort h0, h1, h2, h3, l0, l1, l2, l3;
        split2(a0, h0, l0); split2(a1, h1, l1);
        split2(a2, h2, l2); split2(a3, h3, l3);
        uint2 hv, lv;
        hv.x = (unsigned)h0 | ((unsigned)h1 << 16);
        hv.y = (unsigned)h2 | ((unsigned)h3 << 16);
        lv.x = (unsigned)l0 | ((unsigned)l1 << 16);
        lv.y = (unsigned)l2 | ((unsigned)l3 << 16);
        *(uint2*)&ohi[(size_t)node * ldo + c4] = hv;
        *(uint2*)&olo[(size_t)node * ldo + c4] = lv;
    }
}

// ---------------------------------------------------------------------------
extern "C" void kernel_launch(void* const* d_in, const int* in_sizes, int n_in,
                              void* d_out, int out_size, void* d_ws, size_t ws_size,
                              hipStream_t stream)
{
    const float* features = (const float*)d_in[0];
    const int*   ei       = (const int*)d_in[1];
    const float* W1  = (const float*)d_in[2];
    const float* b1  = (const float*)d_in[3];
    const float* Wc1 = (const float*)d_in[4];
    const float* bc1 = (const float*)d_in[5];
    const float* Wc2 = (const float*)d_in[6];
    const float* bc2 = (const float*)d_in[7];
    const float* W2  = (const float*)d_in[8];
    const float* b2  = (const float*)d_in[9];
    float* out = (float*)d_out;

    const int* src = ei;            // edge_index[0]
    const int* dst = ei + N_EDGES;  // edge_index[1]

    // workspace: bf16 hi/lo planes for all intermediates
    ushort* Xhi  = (ushort*)d_ws;                       // [N][64]
    ushort* Xlo  = Xhi  + (size_t)N_NODES * 64;
    ushort* X1hi = Xlo  + (size_t)N_NODES * 64;         // [N][128]
    ushort* X1lo = X1hi + (size_t)N_NODES * 128;
    ushort* X2hi = X1lo + (size_t)N_NODES * 128;        // [N][256]
    ushort* X2lo = X2hi + (size_t)N_NODES * 256;
    ushort* Ghi  = X2lo + (size_t)N_NODES * 256;        // [N][128] agg scratch
    ushort* Glo  = Ghi  + (size_t)N_NODES * 128;
    ushort* W1Th  = Glo  + (size_t)N_NODES * 128;       // [64][512]
    ushort* W1Tl  = W1Th  + 64 * 512;
    ushort* Wc1Th = W1Tl  + 64 * 512;                   // [64][64]
    ushort* Wc1Tl = Wc1Th + 64 * 64;
    ushort* Wc2Th = Wc1Tl + 64 * 64;                    // [128][128]
    ushort* Wc2Tl = Wc2Th + 128 * 128;
    ushort* W2Th  = Wc2Tl + 128 * 128;                  // [64][448]
    ushort* W2Tl  = W2Th  + 64 * 448;
    int* counts  = (int*)(W2Tl + 64 * 448);
    int* cursor  = counts + N_NODES;
    int* row_ptr = cursor + N_NODES;                    // [N+1]
    int* elist   = row_ptr + (N_NODES + 1);             // [E]
    int* bsum    = elist + N_EDGES;
    int* boff    = bsum + 256;

    const int MB = (N_NODES + 63) / 64;                 // 782 row-tiles
    const int EB = (N_EDGES + 255) / 256;
    const int NB = (N_NODES + 255) / 256;               // 196
    const int AB = (N_NODES + 3) / 4;

    // ---- CSR build ----
    zero_kernel<<<NB, 256, 0, stream>>>(counts, N_NODES);
    count_kernel<<<EB, 256, 0, stream>>>(dst, counts, N_EDGES);
    scan1_kernel<<<NB, 256, 0, stream>>>(counts, row_ptr, bsum, N_NODES);
    scan2_kernel<<<1, 256, 0, stream>>>(bsum, boff, NB);
    scan3_kernel<<<NB, 256, 0, stream>>>(row_ptr, boff, cursor, N_NODES, N_EDGES);
    fill_kernel<<<EB, 256, 0, stream>>>(src, dst, cursor, elist, N_EDGES);

    // ---- weight convert+transpose (split bf16) ----
    convert_wt_kernel<<<(64 * 512 + 255) / 256, 256, 0, stream>>>(W1, 500, 64, 512, 64, W1Th, W1Tl);
    convert_wt_kernel<<<(64 * 64 + 255) / 256, 256, 0, stream>>>(Wc1, 64, 64, 64, 64, Wc1Th, Wc1Tl);
    convert_wt_kernel<<<(128 * 128 + 255) / 256, 256, 0, stream>>>(Wc2, 128, 128, 128, 128, Wc2Th, Wc2Tl);
    convert_wt_kernel<<<(64 * 448 + 255) / 256, 256, 0, stream>>>(W2, 448, 50, 448, 64, W2Th, W2Tl);

    // ---- x = relu(features @ W1 + b1) -> X planes ----
    gemm_feat_kernel<<<MB, 256, 0, stream>>>(features, W1Th, W1Tl, b1, Xhi, Xlo, N_NODES);

    // ---- x11 = A(x) @ Wc1 + bc1 -> X1[:,0:64] ----
    agg_planes_kernel<64><<<AB, 256, 0, stream>>>(Xhi, Xlo, 64, row_ptr, elist, Ghi, Glo, 128, N_NODES);
    gemm_mfma_kernel<64, 0><<<dim3(MB, 1), 256, 0, stream>>>(
        Ghi, Glo, 128, Wc1Th, Wc1Tl, bc1, X1hi, X1lo, 128, N_NODES);

    // ---- x12 = A(x11) @ Wc1 + bc1 -> X1[:,64:128]; G[:,0:64] = A(x11) kept ----
    agg_planes_kernel<64><<<AB, 256, 0, stream>>>(X1hi, X1lo, 128, row_ptr, elist, Ghi, Glo, 128, N_NODES);
    gemm_mfma_kernel<64, 0><<<dim3(MB, 1), 256, 0, stream>>>(
        Ghi, Glo, 128, Wc1Th, Wc1Tl, bc1, X1hi + 64, X1lo + 64, 128, N_NODES);

    // ---- G[:,64:128] = A(x12); x21 = [A(x11)|A(x12)] @ Wc2 + bc2 ----
    agg_planes_kernel<64><<<AB, 256, 0, stream>>>(X1hi + 64, X1lo + 64, 128, row_ptr, elist,
                                                  Ghi + 64, Glo + 64, 128, N_NODES);
    gemm_mfma_kernel<128, 0><<<dim3(MB, 2), 256, 0, stream>>>(
        Ghi, Glo, 128, Wc2Th, Wc2Tl, bc2, X2hi, X2lo, 256, N_NODES);

    // ---- G = A(x21); x22 = G @ Wc2 + bc2 -> X2[:,128:256] ----
    agg_planes_kernel<128><<<AB, 256, 0, stream>>>(X2hi, X2lo, 256, row_ptr, elist, Ghi, Glo, 128, N_NODES);
    gemm_mfma_kernel<128, 0><<<dim3(MB, 2), 256, 0, stream>>>(
        Ghi, Glo, 128, Wc2Th, Wc2Tl, bc2, X2hi + 128, X2lo + 128, 256, N_NODES);

    // ---- out = sigmoid([X|X1|X2] @ W2 + b2) ----
    final_mfma_kernel<<<MB, 256, 0, stream>>>(Xhi, Xlo, X1hi, X1lo, X2hi, X2lo,
                                              W2Th, W2Tl, b2, out, N_NODES);
}